// Round 3
// baseline (511.012 us; speedup 1.0000x reference)
//
#include <hip/hip_runtime.h>
#include <math.h>

#define F1 16
#define F2 8

typedef float f32x4 __attribute__((ext_vector_type(4)));

// Zero the 256 MB output with 16B non-temporal streaming stores, and zero the
// small in-degree counter array (first grid threads).
__global__ void k_zero(f32x4* __restrict__ out, long n4, int* __restrict__ degi, int N) {
    long i = (long)blockIdx.x * blockDim.x + threadIdx.x;
    long stride = (long)gridDim.x * blockDim.x;
    if (i < N) degi[i] = 0;
    f32x4 z = {0.0f, 0.0f, 0.0f, 0.0f};
    for (long j = i; j < n4; j += stride) {
        __builtin_nontemporal_store(z, &out[j]);
    }
}

// Scatter 1.0 at every directed edge position of out AND count in-degree (int).
__global__ void k_edges0(const int* __restrict__ src, const int* __restrict__ dst,
                         float* __restrict__ out, int* __restrict__ degi,
                         int E, int N) {
    int e = blockIdx.x * blockDim.x + threadIdx.x;
    if (e < E) {
        int s = src[e], d = dst[e];
        out[(long)s * N + d] = 1.0f;
        atomicAdd(&degi[d], 1);
    }
}

// Single-block exclusive prefix sum of degi -> rowptr (+ cursor copy) and
// dinv[i] = rsqrt(deg_i + 1).  N <= 1024*items handled by chunking.
__global__ void k_scan(const int* __restrict__ degi, int* __restrict__ rowptr,
                       int* __restrict__ cursor, float* __restrict__ dinv, int N) {
    __shared__ int part[1024];
    int t = threadIdx.x;
    int items = (N + 1023) >> 10;
    int base = t * items;
    int s = 0;
    for (int k = 0; k < items; ++k) {
        int idx = base + k;
        if (idx < N) s += degi[idx];
    }
    part[t] = s;
    __syncthreads();
    // Hillis-Steele inclusive scan over the 1024 partials
    for (int off = 1; off < 1024; off <<= 1) {
        int v = (t >= off) ? part[t - off] : 0;
        __syncthreads();
        part[t] += v;
        __syncthreads();
    }
    int run = (t == 0) ? 0 : part[t - 1];
    for (int k = 0; k < items; ++k) {
        int idx = base + k;
        if (idx < N) {
            int dg = degi[idx];
            rowptr[idx] = run;
            cursor[idx] = run;
            dinv[idx] = rsqrtf((float)(dg + 1));
            run += dg;
        }
    }
}

// Counting-sort pass: bucket src indices by dst.
__global__ void k_bucket(const int* __restrict__ src, const int* __restrict__ dst,
                         int* __restrict__ cursor, int* __restrict__ sby, int E) {
    int e = blockIdx.x * blockDim.x + threadIdx.x;
    if (e < E) {
        int d = dst[e];
        int pos = atomicAdd(&cursor[d], 1);
        sby[pos] = src[e];
    }
}

// Fused conv1 (gather, no atomics) + bias + relu + 16x8 matmul -> h2.
// 16 lanes per node (lane f owns feature f); W1 row loads are one 64B line.
__global__ void k_conv1(const int* __restrict__ rowptr, const int* __restrict__ degi,
                        const int* __restrict__ sby, const float* __restrict__ dinv,
                        const float* __restrict__ W1, const float* __restrict__ b1,
                        const float* __restrict__ W2, float* __restrict__ h2, int N) {
    int tid = blockIdx.x * blockDim.x + threadIdx.x;
    int node = tid >> 4;
    int f = tid & (F1 - 1);
    if (node >= N) return;
    int r0 = rowptr[node];
    int r1 = r0 + degi[node];
    float acc = 0.0f;
    for (int k = r0; k < r1; ++k) {
        int s = sby[k];
        acc += dinv[s] * W1[(long)s * F1 + f];
    }
    float di = dinv[node];
    float x = di * acc + di * di * W1[(long)node * F1 + f] + b1[f];
    float rv = x > 0.0f ? x : 0.0f;
    // cross-lane 16 -> 8 matmul: lanes of this 16-group each hold r[f]
    int lane = threadIdx.x & 63;
    int gbase = lane & ~(F1 - 1);
    int g = f & (F2 - 1);          // lanes 8..15 compute duplicates (no OOB)
    float hg = 0.0f;
    #pragma unroll
    for (int ff = 0; ff < F1; ++ff) {
        float rf = __shfl(rv, gbase + ff, 64);
        hg += rf * W2[ff * F2 + g];
    }
    if (f < F2) h2[(long)node * F2 + g] = hg;
}

// Fused conv2 (gather, no atomics) + self term + bias + relu -> final embedding xf.
// 8 lanes per node.
__global__ void k_conv2(const int* __restrict__ rowptr, const int* __restrict__ degi,
                        const int* __restrict__ sby, const float* __restrict__ dinv,
                        const float* __restrict__ h2, const float* __restrict__ b2,
                        float* __restrict__ xf, int N) {
    int tid = blockIdx.x * blockDim.x + threadIdx.x;
    int node = tid >> 3;
    int g = tid & (F2 - 1);
    if (node >= N) return;
    int r0 = rowptr[node];
    int r1 = r0 + degi[node];
    float acc = 0.0f;
    for (int k = r0; k < r1; ++k) {
        int s = sby[k];
        acc += dinv[s] * h2[(long)s * F2 + g];
    }
    float di = dinv[node];
    float x = di * acc + di * di * h2[(long)node * F2 + g] + b2[g];
    xf[(long)node * F2 + g] = x > 0.0f ? x : 0.0f;
}

// Per undirected edge: score from precomputed embeddings, sigmoid, scatter.
__global__ void k_orient(const int2* __restrict__ ue, const float* __restrict__ xf,
                         const float* __restrict__ Wfc, const float* __restrict__ bfc,
                         float* __restrict__ out, int U, int N) {
    int k = blockIdx.x * blockDim.x + threadIdx.x;
    if (k < U) {
        int2 e = ue[k];
        int u = e.x, v = e.y;
        const f32x4* x4 = (const f32x4*)xf;
        f32x4 ua = x4[(long)u * 2], ub = x4[(long)u * 2 + 1];
        f32x4 va = x4[(long)v * 2], vb = x4[(long)v * 2 + 1];
        const f32x4* w4 = (const f32x4*)Wfc;
        f32x4 wu0 = w4[0], wu1 = w4[1], wv0 = w4[2], wv1 = w4[3];
        float s = bfc[0];
        #pragma unroll
        for (int g = 0; g < 4; ++g) {
            s += ua[g] * wu0[g] + ub[g] * wu1[g] + va[g] * wv0[g] + vb[g] * wv1[g];
        }
        float o = 1.0f / (1.0f + expf(-s));
        out[(long)u * N + v] = o;
        out[(long)v * N + u] = 1.0f - o;
    }
}

extern "C" void kernel_launch(void* const* d_in, const int* in_sizes, int n_in,
                              void* d_out, int out_size, void* d_ws, size_t ws_size,
                              hipStream_t stream) {
    const float* W1  = (const float*)d_in[1];
    const float* b1  = (const float*)d_in[2];
    const float* W2  = (const float*)d_in[3];
    const float* b2  = (const float*)d_in[4];
    const float* Wfc = (const float*)d_in[5];
    const float* bfc = (const float*)d_in[6];
    const int* edge_index = (const int*)d_in[7];
    const int2* und       = (const int2*)d_in[8];

    int N = in_sizes[1] / F1;      // 8192
    int E = in_sizes[7] / 2;
    int U = in_sizes[8] / 2;
    const int* src = edge_index;
    const int* dst = edge_index + E;

    // ws layout (4B words): degi[N] | rowptr[N] | cursor[N] | dinv[N] |
    //                       sby[E] | h2[8N] | xf[8N]
    int*   degi   = (int*)d_ws;
    int*   rowptr = degi + N;
    int*   cursor = rowptr + N;
    float* dinv   = (float*)(cursor + N);
    int*   sby    = (int*)(dinv + N);
    float* h2     = (float*)(sby + E);
    float* xf     = h2 + (long)F2 * N;

    const int B = 256;

    // 1) zero out (268 MB streaming) + zero degi
    {
        long n4 = ((long)N * N) / 4;
        k_zero<<<2048, B, 0, stream>>>((f32x4*)d_out, n4, degi, N);
    }
    // 2) ones-scatter + in-degree count
    k_edges0<<<(E + B - 1) / B, B, 0, stream>>>(src, dst, (float*)d_out, degi, E, N);
    // 3) prefix scan -> rowptr/cursor, dinv
    k_scan<<<1, 1024, 0, stream>>>(degi, rowptr, cursor, dinv, N);
    // 4) bucket srcs by dst (counting sort)
    k_bucket<<<(E + B - 1) / B, B, 0, stream>>>(src, dst, cursor, sby, E);
    // 5) conv1 gather + layer1 (atomic-free)
    k_conv1<<<(N * F1 + B - 1) / B, B, 0, stream>>>(rowptr, degi, sby, dinv,
                                                    W1, b1, W2, h2, N);
    // 6) conv2 gather + self + relu -> final embeddings (atomic-free)
    k_conv2<<<(N * F2 + B - 1) / B, B, 0, stream>>>(rowptr, degi, sby, dinv,
                                                    h2, b2, xf, N);
    // 7) orient scoring + scatter
    k_orient<<<(U + B - 1) / B, B, 0, stream>>>(und, xf, Wfc, bfc, (float*)d_out, U, N);
}

// Round 4
// 452.467 us; speedup vs baseline: 1.1294x; 1.1294x over previous
//
#include <hip/hip_runtime.h>
#include <math.h>

#define F1 16
#define F2 8

typedef float f32x4 __attribute__((ext_vector_type(4)));

// Per edge: count in-degree (int atomics) + default edge value 1.0.
// Per node (id <= N): rowptr[id] = lower_bound(src, id)  (src is sorted,
// since edge_index = np.nonzero(A) is row-major ordered).
__global__ void k_prep(const int* __restrict__ src, const int* __restrict__ dst,
                       int* __restrict__ degi, float* __restrict__ val,
                       int* __restrict__ rowptr, int E, int N) {
    int id = blockIdx.x * blockDim.x + threadIdx.x;
    if (id < E) {
        atomicAdd(&degi[dst[id]], 1);
        val[id] = 1.0f;
    }
    if (id <= N) {
        int lo = 0, hi = E;
        while (lo < hi) {
            int mid = (lo + hi) >> 1;
            if (src[mid] < id) lo = mid + 1; else hi = mid;
        }
        rowptr[id] = lo;
    }
}

// conv1 aggregation: x1[dst] += norm * W1[src]; norm inline from degi.
// (x1 pre-zeroed by memset) 16 threads per edge, one feature each.
__global__ void k_conv1_edges(const int* __restrict__ src, const int* __restrict__ dst,
                              const int* __restrict__ degi, const float* __restrict__ W1,
                              float* __restrict__ x1, int E) {
    int id = blockIdx.x * blockDim.x + threadIdx.x;
    int e = id >> 4;
    int f = id & (F1 - 1);
    if (e < E) {
        int s = src[e], d = dst[e];
        float nrm = rsqrtf((float)((degi[s] + 1) * (degi[d] + 1)));
        atomicAdd(&x1[(long)d * F1 + f], nrm * W1[(long)s * F1 + f]);
    }
}

// Per (node, out-feature): r = relu(x1 + W1/(deg+1) + b1); h2[i,g] = sum_f r[f]*W2[f,g]
__global__ void k_layer1(const int* __restrict__ degi, const float* __restrict__ b1,
                         const float* __restrict__ W1, const float* __restrict__ W2,
                         const float* __restrict__ x1, float* __restrict__ h2, int N) {
    int id = blockIdx.x * blockDim.x + threadIdx.x;
    if (id < N * F2) {
        int i = id >> 3;        // node
        int g = id & (F2 - 1);  // out feature
        float sw = 1.0f / (float)(degi[i] + 1);
        float acc = 0.0f;
        #pragma unroll
        for (int f = 0; f < F1; ++f) {
            float v = x1[(long)i * F1 + f] + sw * W1[(long)i * F1 + f] + b1[f];
            v = v > 0.0f ? v : 0.0f;
            acc += v * W2[f * F2 + g];
        }
        h2[(long)i * F2 + g] = acc;
    }
}

// conv2 aggregation: x2[dst] += norm * h2[src]; norm inline from degi.
__global__ void k_conv2_edges(const int* __restrict__ src, const int* __restrict__ dst,
                              const int* __restrict__ degi, const float* __restrict__ h2,
                              float* __restrict__ x2, int E) {
    int id = blockIdx.x * blockDim.x + threadIdx.x;
    int e = id >> 3;
    int g = id & (F2 - 1);
    if (e < E) {
        int s = src[e], d = dst[e];
        float nrm = rsqrtf((float)((degi[s] + 1) * (degi[d] + 1)));
        atomicAdd(&x2[(long)d * F2 + g], nrm * h2[(long)s * F2 + g]);
    }
}

// Per undirected edge: finish conv2 inline, score, sigmoid; then write orient
// into the sparse val[] array at the two directed-edge slots, found by binary
// search over the (sorted) dst list of each row.
__global__ void k_orient2(const int2* __restrict__ ue, const float* __restrict__ x2,
                          const float* __restrict__ h2, const int* __restrict__ degi,
                          const float* __restrict__ b2, const float* __restrict__ Wfc,
                          const float* __restrict__ bfc, const int* __restrict__ rowptr,
                          const int* __restrict__ dst, float* __restrict__ val, int U) {
    int k = blockIdx.x * blockDim.x + threadIdx.x;
    if (k >= U) return;
    int2 e = ue[k];
    int u = e.x, v = e.y;
    float swu = 1.0f / (float)(degi[u] + 1);
    float swv = 1.0f / (float)(degi[v] + 1);
    float s = bfc[0];
    #pragma unroll
    for (int g = 0; g < F2; ++g) {
        float xu = x2[(long)u * F2 + g] + swu * h2[(long)u * F2 + g] + b2[g];
        float xv = x2[(long)v * F2 + g] + swv * h2[(long)v * F2 + g] + b2[g];
        xu = xu > 0.0f ? xu : 0.0f;
        xv = xv > 0.0f ? xv : 0.0f;
        s += xu * Wfc[g] + xv * Wfc[F2 + g];
    }
    float o = 1.0f / (1.0f + expf(-s));
    // slot of (u, v)
    int lo = rowptr[u], hi = rowptr[u + 1];
    while (lo < hi) { int mid = (lo + hi) >> 1; if (dst[mid] < v) lo = mid + 1; else hi = mid; }
    if (lo < rowptr[u + 1] && dst[lo] == v) val[lo] = o;
    // slot of (v, u)
    lo = rowptr[v]; hi = rowptr[v + 1];
    while (lo < hi) { int mid = (lo + hi) >> 1; if (dst[mid] < u) lo = mid + 1; else hi = mid; }
    if (lo < rowptr[v + 1] && dst[lo] == u) val[lo] = 1.0f - o;
}

// Single-pass output: one workgroup per row. Zero the row with coalesced f32x4
// stores (regular stores -> lines stay L2-hot), barrier, then overwrite this
// row's edge positions from val[] while the lines are still resident.
// Output HBM traffic = exactly N*N*4 bytes, written once, no RMW re-fetch.
__global__ void __launch_bounds__(256) k_writeout(const int* __restrict__ rowptr,
                                                  const int* __restrict__ dst,
                                                  const float* __restrict__ val,
                                                  float* __restrict__ out, int N) {
    int row = blockIdx.x;
    int t = threadIdx.x;
    int n4 = N >> 2;                       // f32x4 per row
    f32x4* out4 = (f32x4*)(out + (long)row * N);
    f32x4 z = {0.0f, 0.0f, 0.0f, 0.0f};
    for (int j = t; j < n4; j += 256) out4[j] = z;
    __syncthreads();
    int r0 = rowptr[row], r1 = rowptr[row + 1];
    float* orow = out + (long)row * N;
    for (int k = r0 + t; k < r1; k += 256) orow[dst[k]] = val[k];
}

extern "C" void kernel_launch(void* const* d_in, const int* in_sizes, int n_in,
                              void* d_out, int out_size, void* d_ws, size_t ws_size,
                              hipStream_t stream) {
    const float* W1  = (const float*)d_in[1];
    const float* b1  = (const float*)d_in[2];
    const float* W2  = (const float*)d_in[3];
    const float* b2  = (const float*)d_in[4];
    const float* Wfc = (const float*)d_in[5];
    const float* bfc = (const float*)d_in[6];
    const int* edge_index = (const int*)d_in[7];
    const int2* und       = (const int2*)d_in[8];

    int N = in_sizes[1] / F1;      // 8192
    int E = in_sizes[7] / 2;
    int U = in_sizes[8] / 2;
    const int* src = edge_index;
    const int* dst = edge_index + E;

    // ws layout (4B words):
    //   [degi(N) | x1(16N) | x2(8N)]  <- zeroed by one memset (100N B = 800 KB)
    //   h2(8N) | rowptr(N+1) | val(E)  <- fully written before read
    int*   degi   = (int*)d_ws;
    float* x1     = (float*)(degi + N);
    float* x2     = x1 + (long)F1 * N;
    float* h2     = x2 + (long)F2 * N;
    int*   rowptr = (int*)(h2 + (long)F2 * N);
    float* val    = (float*)(rowptr + N + 1);

    const int B = 256;

    (void)hipMemsetAsync(d_ws, 0, (size_t)(N + (long)F1 * N + (long)F2 * N) * sizeof(float), stream);

    // degree count + val=1 + rowptr (binary search over sorted src)
    {
        int work = (E > N + 1) ? E : (N + 1);
        k_prep<<<(work + B - 1) / B, B, 0, stream>>>(src, dst, degi, val, rowptr, E, N);
    }
    // conv1 aggregation (atomic scatter — measured faster than CSR gather)
    {
        long work = (long)E * F1;
        k_conv1_edges<<<(int)((work + B - 1) / B), B, 0, stream>>>(src, dst, degi, W1, x1, E);
    }
    // layer1: relu + 16x8 matmul
    k_layer1<<<(N * F2 + B - 1) / B, B, 0, stream>>>(degi, b1, W1, W2, x1, h2, N);
    // conv2 aggregation
    {
        long work = (long)E * F2;
        k_conv2_edges<<<(int)((work + B - 1) / B), B, 0, stream>>>(src, dst, degi, h2, x2, E);
    }
    // orient scoring -> sparse val[] (no output RMW)
    k_orient2<<<(U + B - 1) / B, B, 0, stream>>>(und, x2, h2, degi, b2, Wfc, bfc,
                                                 rowptr, dst, val, U);
    // single-pass output construction
    k_writeout<<<N, B, 0, stream>>>(rowptr, dst, val, (float*)d_out, N);
}